// Round 1
// baseline (122.227 us; speedup 1.0000x reference)
//
#include <hip/hip_runtime.h>
#include <stdint.h>
#include <math.h>

// Problem constants (B, C, K from reference)
constexpr int NB = 8;
constexpr int NC = 32;
constexpr int NK = 512;

// ---------------------------------------------------------------------------
// Threefry2x32 (Random123 / JAX), rotations {13,15,26,6} / {17,29,16,24}
// ---------------------------------------------------------------------------
__device__ __forceinline__ uint32_t rotl32(uint32_t x, uint32_t r) {
    return (x << r) | (x >> (32u - r));
}

__device__ __forceinline__ void threefry2x32(uint32_t k0, uint32_t k1,
                                             uint32_t x0, uint32_t x1,
                                             uint32_t& o0, uint32_t& o1) {
    const uint32_t ks2 = k0 ^ k1 ^ 0x1BD11BDAu;
    x0 += k0; x1 += k1;

    x0 += x1; x1 = rotl32(x1, 13); x1 ^= x0;
    x0 += x1; x1 = rotl32(x1, 15); x1 ^= x0;
    x0 += x1; x1 = rotl32(x1, 26); x1 ^= x0;
    x0 += x1; x1 = rotl32(x1,  6); x1 ^= x0;
    x0 += k1; x1 += ks2 + 1u;

    x0 += x1; x1 = rotl32(x1, 17); x1 ^= x0;
    x0 += x1; x1 = rotl32(x1, 29); x1 ^= x0;
    x0 += x1; x1 = rotl32(x1, 16); x1 ^= x0;
    x0 += x1; x1 = rotl32(x1, 24); x1 ^= x0;
    x0 += ks2; x1 += k0 + 2u;

    x0 += x1; x1 = rotl32(x1, 13); x1 ^= x0;
    x0 += x1; x1 = rotl32(x1, 15); x1 ^= x0;
    x0 += x1; x1 = rotl32(x1, 26); x1 ^= x0;
    x0 += x1; x1 = rotl32(x1,  6); x1 ^= x0;
    x0 += k0; x1 += k1 + 3u;

    x0 += x1; x1 = rotl32(x1, 17); x1 ^= x0;
    x0 += x1; x1 = rotl32(x1, 29); x1 ^= x0;
    x0 += x1; x1 = rotl32(x1, 16); x1 ^= x0;
    x0 += x1; x1 = rotl32(x1, 24); x1 ^= x0;
    x0 += k1; x1 += ks2 + 4u;

    x0 += x1; x1 = rotl32(x1, 13); x1 ^= x0;
    x0 += x1; x1 = rotl32(x1, 15); x1 ^= x0;
    x0 += x1; x1 = rotl32(x1, 26); x1 ^= x0;
    x0 += x1; x1 = rotl32(x1,  6); x1 ^= x0;
    x0 += ks2; x1 += k0 + 5u;

    o0 = x0; o1 = x1;
}

// JAX partitionable-threefry 32-bit random bits for flat element index n,
// key = (0, 42) from jax.random.key(42).
// bits(n) = o0 ^ o1 of threefry2x32(key, n>>32, n&0xffffffff)
__device__ __forceinline__ uint32_t jax_random_bits(uint64_t n) {
    uint32_t o0, o1;
    threefry2x32(0u, 42u, (uint32_t)(n >> 32), (uint32_t)n, o0, o1);
    return o0 ^ o1;
}

// jax.random.uniform bit->float: (bits>>9 | 0x3f800000) as float - 1.0 (exact),
// then scale to [minval, maxval) = [1e-10, 1.0). Done in f64 (np-style ref).
__device__ __forceinline__ double gumbel_from_bits(uint32_t bits) {
    uint32_t fb = (bits >> 9) | 0x3F800000u;
    float bf = __uint_as_float(fb) - 1.0f;           // exact, [0,1), 23-bit
    double u = (double)bf * (1.0 - 1e-10) + 1e-10;
    u = fmax(1e-10, u);
    return -log(-log(u));
}

// ---------------------------------------------------------------------------
__global__ void zero_out_kernel(float4* __restrict__ out) {
    out[blockIdx.x * blockDim.x + threadIdx.x] = make_float4(0.f, 0.f, 0.f, 0.f);
}

__global__ __launch_bounds__(256) void sample_row_kernel(
    const float* __restrict__ amp, const float* __restrict__ ph,
    const float* __restrict__ A, const float* __restrict__ wav,
    const float* __restrict__ wpv, float* __restrict__ out)
{
    const int i   = blockIdx.x;   // row index 0..K-1
    const int b   = blockIdx.y;   // batch 0..B-1
    const int tid = threadIdx.x;  // 0..255

    __shared__ double fi[NC];
    __shared__ double smin[4];
    __shared__ double s_dmin;

    const double wa = (double)wav[0];
    const double wp = (double)wpv[0];

    if (tid < NC) {
        int idx = (b * NC + tid) * NK + i;
        fi[tid] = wa * (double)amp[idx] + wp * (double)ph[idx];
    }
    __syncthreads();

    // Each thread owns columns j = tid and j = tid + 256.
    double denom[2];
    double localmin = 1e300;
    #pragma unroll
    for (int it = 0; it < 2; ++it) {
        const int j = tid + it * 256;
        double acc = 0.0;
        #pragma unroll
        for (int c = 0; c < NC; ++c) {
            int idx = (b * NC + c) * NK + j;
            double fj = wa * (double)amp[idx] + wp * (double)ph[idx];
            double d = fi[c] - fj;
            acc = fma(d, d, acc);
        }
        double ad = (double)A[j * NK + j];
        double dist = acc * (ad * ad);
        double den = dist + 1e-10;   // denominator of exp_dist
        denom[it] = den;
        if (j != i) localmin = fmin(localmin, den);
    }

    // Row min of denom over j != i  (=> exp_max = fl(1/dmin), monotone fl)
    double m = localmin;
    #pragma unroll
    for (int off = 32; off > 0; off >>= 1)
        m = fmin(m, __shfl_down(m, off));
    if ((tid & 63) == 0) smin[tid >> 6] = m;
    __syncthreads();
    if (tid == 0)
        s_dmin = fmin(fmin(smin[0], smin[1]), fmin(smin[2], smin[3]));
    __syncthreads();

    const double exp_max = 1.0 / s_dmin;

    #pragma unroll
    for (int it = 0; it < 2; ++it) {
        const int j = tid + it * 256;
        double p;
        if (j == i) {
            p = 0.99;                                  // (0*offdiag + eye)*0.99
        } else {
            double e = 1.0 / denom[it];                // exp_dist
            p = (e / exp_max) * 0.99;                  // (p*offdiag)*0.99
        }
        double logit = log(p / (1.0 - p));

        // logits flat index into shape (B, K, K, 2)
        uint64_t base = 2ull * ((((uint64_t)b * NK) + i) * NK + j);
        double g0 = gumbel_from_bits(jax_random_bits(base));
        double g1 = gumbel_from_bits(jax_random_bits(base + 1));

        // sample = 1 iff argmax([logit+g0, -logit+g1]) == 0 (ties -> first)
        double z0 = logit + g0;
        double z1 = -logit + g1;
        if (z0 >= z1) {
            atomicAdd(&out[i * NK + j], 0.125f);  // mean over B=8, exact
        }
    }
}

extern "C" void kernel_launch(void* const* d_in, const int* in_sizes, int n_in,
                              void* d_out, int out_size, void* d_ws, size_t ws_size,
                              hipStream_t stream) {
    const float* amp = (const float*)d_in[0];   // (8,32,512)
    const float* ph  = (const float*)d_in[1];   // (8,32,512)
    const float* A   = (const float*)d_in[2];   // (512,512)
    const float* wa  = (const float*)d_in[3];   // scalar
    const float* wp  = (const float*)d_in[4];   // scalar
    float* out = (float*)d_out;                 // (512,512) f32

    // d_out is poisoned 0xAA before every launch -> zero it first.
    // 512*512 floats = 65536 float4
    zero_out_kernel<<<256, 256, 0, stream>>>((float4*)out);

    dim3 grid(NK, NB);
    sample_row_kernel<<<grid, 256, 0, stream>>>(amp, ph, A, wa, wp, out);
}

// Round 2
// 93.602 us; speedup vs baseline: 1.3058x; 1.3058x over previous
//
#include <hip/hip_runtime.h>
#include <stdint.h>
#include <math.h>

constexpr int NB = 8;
constexpr int NC = 32;
constexpr int NK = 512;
constexpr int ROWS = 4;          // rows (i) per block in the main kernel

// ---------------------------------------------------------------------------
// Threefry2x32 (Random123 / JAX), key = (0, 42), x0 = 0 (flat idx < 2^32)
// ---------------------------------------------------------------------------
__device__ __forceinline__ uint32_t rotl32(uint32_t x, uint32_t r) {
    return (x << r) | (x >> (32u - r));
}

__device__ __forceinline__ uint32_t jax_random_bits(uint32_t n) {
    const uint32_t k0 = 0u, k1 = 42u;
    const uint32_t ks2 = k0 ^ k1 ^ 0x1BD11BDAu;
    uint32_t x0 = 0u + k0, x1 = n + k1;

    x0 += x1; x1 = rotl32(x1, 13); x1 ^= x0;
    x0 += x1; x1 = rotl32(x1, 15); x1 ^= x0;
    x0 += x1; x1 = rotl32(x1, 26); x1 ^= x0;
    x0 += x1; x1 = rotl32(x1,  6); x1 ^= x0;
    x0 += k1; x1 += ks2 + 1u;

    x0 += x1; x1 = rotl32(x1, 17); x1 ^= x0;
    x0 += x1; x1 = rotl32(x1, 29); x1 ^= x0;
    x0 += x1; x1 = rotl32(x1, 16); x1 ^= x0;
    x0 += x1; x1 = rotl32(x1, 24); x1 ^= x0;
    x0 += ks2; x1 += k0 + 2u;

    x0 += x1; x1 = rotl32(x1, 13); x1 ^= x0;
    x0 += x1; x1 = rotl32(x1, 15); x1 ^= x0;
    x0 += x1; x1 = rotl32(x1, 26); x1 ^= x0;
    x0 += x1; x1 = rotl32(x1,  6); x1 ^= x0;
    x0 += k0; x1 += k1 + 3u;

    x0 += x1; x1 = rotl32(x1, 17); x1 ^= x0;
    x0 += x1; x1 = rotl32(x1, 29); x1 ^= x0;
    x0 += x1; x1 = rotl32(x1, 16); x1 ^= x0;
    x0 += x1; x1 = rotl32(x1, 24); x1 ^= x0;
    x0 += k1; x1 += ks2 + 4u;

    x0 += x1; x1 = rotl32(x1, 13); x1 ^= x0;
    x0 += x1; x1 = rotl32(x1, 15); x1 ^= x0;
    x0 += x1; x1 = rotl32(x1, 26); x1 ^= x0;
    x0 += x1; x1 = rotl32(x1,  6); x1 ^= x0;
    x0 += ks2; x1 += k0 + 5u;

    return x0 ^ x1;   // partitionable threefry: o0 ^ o1
}

// u (f64, JAX-exact) and fast f32 L = -log(u).
// bf = 23-bit uniform in [0,1) (exact); u = bf*(1-1e-10) + 1e-10.
__device__ __forceinline__ float fastL(uint32_t bits, double& ud) {
    const double S = 1.0 - 1e-10, T = 1e-10;
    uint32_t fb = (bits >> 9) | 0x3F800000u;
    float bf = __uint_as_float(fb) - 1.0f;            // exact
    ud = (double)bf * S + T;                          // >= 1e-10 by construction
    if (bf <= 0.5f) {
        return -logf((float)ud);                      // u in [1e-10, ~0.5]
    } else {
        double vm1 = S * ((double)bf - 1.0);          // u-1, exact-ish in f64
        return -log1pf((float)vm1);                   // u near 1: log1p form
    }
}

// Decision: sample==1 iff logit+g0 >= -logit+g1  <=>  a2*L1 >= c2*L0
// a2 = (0.99*Dm)^2, c2 = (D - 0.99*Dm)^2  (diag: a2=99^2, c2=1)
__device__ __forceinline__ bool decide(double D, double q /*0.99*Dm*/,
                                       bool diag, uint32_t n0) {
    uint32_t bits0 = jax_random_bits(n0);
    uint32_t bits1 = jax_random_bits(n0 + 1u);
    double u0d, u1d;
    float L0f = fastL(bits0, u0d);
    float L1f = fastL(bits1, u1d);

    double a2d, c2d;
    if (diag) { a2d = 9801.0; c2d = 1.0; }
    else      { a2d = q * q; double t = D - q; c2d = t * t; }

    float lhs = (float)a2d * L1f;
    float rhs = (float)c2d * L0f;
    float diff = lhs - rhs;
    if (fabsf(diff) > 1e-4f * (lhs + rhs))
        return diff >= 0.0f;                          // fast path (sign-safe)

    // rare fallback (~2e-4 of elements): full f64, matches round-1 decisions
    double L0 = -log(u0d);
    double L1 = -log(u1d);
    return a2d * L1 >= c2d * L0;
}

// ---------------------------------------------------------------------------
// Prep: zero out (512*512 f32), F[b,c,j] = wa*amp + wp*ph (f64), Ad2[j]=A_jj^2
// grid 1024 x 256 = 262144 threads
// ---------------------------------------------------------------------------
__global__ void prep_kernel(const float* __restrict__ amp,
                            const float* __restrict__ ph,
                            const float* __restrict__ A,
                            const float* __restrict__ wav,
                            const float* __restrict__ wpv,
                            double* __restrict__ F,
                            double* __restrict__ Ad2,
                            float* __restrict__ out) {
    int t = blockIdx.x * 256 + threadIdx.x;
    out[t] = 0.0f;
    if (t < NB * NC * NK) {
        double wa = (double)wav[0], wp = (double)wpv[0];
        F[t] = wa * (double)amp[t] + wp * (double)ph[t];
    }
    if (t < NK) {
        double a = (double)A[t * NK + t];
        Ad2[t] = a * a;
    }
}

// ---------------------------------------------------------------------------
// Main: grid (NK/ROWS, NB) x 256 threads; thread owns cols j=tid, tid+256
// for ROWS rows i0..i0+3 of its batch b.
// ---------------------------------------------------------------------------
__global__ __launch_bounds__(256) void sample_kernel(
    const double* __restrict__ F, const double* __restrict__ Ad2,
    float* __restrict__ out)
{
    const int i0  = blockIdx.x * ROWS;
    const int b   = blockIdx.y;
    const int tid = threadIdx.x;

    __shared__ double fi[ROWS][NC];
    __shared__ double sred[ROWS][4];
    __shared__ double s_q[ROWS];

    const double* Fb = F + (size_t)b * NC * NK;

    if (tid < ROWS * NC) {
        int r = tid >> 5, c = tid & 31;
        fi[r][c] = Fb[c * NK + (i0 + r)];
    }
    __syncthreads();

    // dist accumulation: same fma order as round-1 (bit-identical D)
    double acc[2][ROWS];
    #pragma unroll
    for (int it = 0; it < 2; ++it)
        #pragma unroll
        for (int r = 0; r < ROWS; ++r) acc[it][r] = 0.0;

    #pragma unroll 4
    for (int c = 0; c < NC; ++c) {
        double fj0 = Fb[c * NK + tid];
        double fj1 = Fb[c * NK + tid + 256];
        #pragma unroll
        for (int r = 0; r < ROWS; ++r) {
            double fic = fi[r][c];
            double d0 = fic - fj0; acc[0][r] = fma(d0, d0, acc[0][r]);
            double d1 = fic - fj1; acc[1][r] = fma(d1, d1, acc[1][r]);
        }
    }

    double D[2][ROWS];
    #pragma unroll
    for (int it = 0; it < 2; ++it) {
        int j = tid + it * 256;
        double a2 = Ad2[j];
        #pragma unroll
        for (int r = 0; r < ROWS; ++r) {
            double dist = acc[it][r] * a2;   // two roundings, as round-1
            D[it][r] = dist + 1e-10;
        }
    }

    // per-row min over j != i (min is order-independent -> bit-identical)
    #pragma unroll
    for (int r = 0; r < ROWS; ++r) {
        const int i = i0 + r;
        double m = 1e300;
        #pragma unroll
        for (int it = 0; it < 2; ++it) {
            int j = tid + it * 256;
            if (j != i) m = fmin(m, D[it][r]);
        }
        #pragma unroll
        for (int off = 32; off > 0; off >>= 1)
            m = fmin(m, __shfl_down(m, off));
        if ((tid & 63) == 0) sred[r][tid >> 6] = m;
    }
    __syncthreads();
    if (tid < ROWS) {
        double m = fmin(fmin(sred[tid][0], sred[tid][1]),
                        fmin(sred[tid][2], sred[tid][3]));
        s_q[tid] = 0.99 * m;
    }
    __syncthreads();

    #pragma unroll
    for (int it = 0; it < 2; ++it) {
        const int j = tid + it * 256;
        #pragma unroll
        for (int r = 0; r < ROWS; ++r) {
            const int i = i0 + r;
            // flat index into (B,K,K,2)
            uint32_t n0 = 2u * (((uint32_t)(b * NK + i)) * NK + (uint32_t)j);
            if (decide(D[it][r], s_q[r], j == i, n0))
                atomicAdd(&out[i * NK + j], 0.125f);   // mean over B=8, exact
        }
    }
}

extern "C" void kernel_launch(void* const* d_in, const int* in_sizes, int n_in,
                              void* d_out, int out_size, void* d_ws, size_t ws_size,
                              hipStream_t stream) {
    const float* amp = (const float*)d_in[0];   // (8,32,512)
    const float* ph  = (const float*)d_in[1];   // (8,32,512)
    const float* A   = (const float*)d_in[2];   // (512,512)
    const float* wa  = (const float*)d_in[3];   // scalar
    const float* wp  = (const float*)d_in[4];   // scalar
    float* out = (float*)d_out;                 // (512,512) f32

    double* F   = (double*)d_ws;                       // 131072 f64 = 1 MB
    double* Ad2 = (double*)d_ws + NB * NC * NK;        // 512 f64

    prep_kernel<<<1024, 256, 0, stream>>>(amp, ph, A, wa, wp, F, Ad2, out);

    dim3 grid(NK / ROWS, NB);
    sample_kernel<<<grid, 256, 0, stream>>>(F, Ad2, out);
}